// Round 17
// baseline (282.702 us; speedup 1.0000x reference)
//
#include <hip/hip_runtime.h>

typedef _Float16 h2_t __attribute__((ext_vector_type(2)));
typedef _Float16 f16x8 __attribute__((ext_vector_type(8)));
typedef float f32x4 __attribute__((ext_vector_type(4)));
typedef unsigned u32x4 __attribute__((ext_vector_type(4)));

#define DI __device__ __forceinline__

#if __has_builtin(__builtin_amdgcn_sched_barrier)
#define SCHED_FENCE() __builtin_amdgcn_sched_barrier(0)
#else
#define SCHED_FENCE()
#endif

constexpr int PAW = 96;          // xt pitch (halfs): 192 B rows, 16B-aligned + XOR swizzle
constexpr int PBV = 72;          // hb pitch (halfs): 144 B rows = 9*16 -> b128-aligned
constexpr int TILE = 64 * PAW;   // one staged image plane: 6144 halfs
constexpr int PLANE = 64 * PBV;  // one hb plane: 4608 halfs
constexpr float kC1 = 1.0e-4f;   // (0.01*1)^2
constexpr float kC2 = 9.0e-4f;   // (0.03*1)^2
constexpr float kALPHA = 0.025f;

DI float rcp_fast(float v) { return __builtin_amdgcn_rcpf(v); }

DI float fdot2f(h2_t a, h2_t b, float c) {
#if __has_builtin(__builtin_amdgcn_fdot2)
  return __builtin_amdgcn_fdot2(a, b, c, false);   // v_dot2_f32_f16
#else
  return c + (float)(a.x) * (float)(b.x) + (float)(a.y) * (float)(b.y);
#endif
}

DI h2_t w2h(unsigned u) { return __builtin_bit_cast(h2_t, u); }

DI f16x8 ldfrag(const _Float16* __restrict__ p) {
  return *reinterpret_cast<const f16x8*>(p);
}

DI f32x4 mfma16(f16x8 a, f16x8 b, f32x4 c) {
  return __builtin_amdgcn_mfma_f32_16x16x32_f16(a, b, c, 0, 0, 0);
}

DI f16x8 pkabs8(f16x8 v) {
  u32x4 u = __builtin_bit_cast(u32x4, v);
  u32x4 msk = {0x7FFF7FFFu, 0x7FFF7FFFu, 0x7FFF7FFFu, 0x7FFF7FFFu};
  u &= msk;
  return __builtin_bit_cast(f16x8, u);
}

// ---- fused horizontal conv as MFMA: all fields in ONE pass (R10 layout) ----
// A = weights (m = out-col), B = data frags.  Fields {x,y,x^2+y^2,x*y(,|x-y|)}
// -> planes 0..3(,4) from ONE set of xt/yt reads.  b16 stores (R16 lesson:
// b64 operand-swap DOUBLED bank conflicts, 199->211 us -- instr count is NOT
// the limiter).  FENCES RELAXED to every 2 nt (was every nt): we are
// LDS-capped at 2 blocks/CU, so VGPR headroom to 256 is free -- letting
// nt+1's ds_read_b128 (~120 cyc) issue under nt's MFMAs attacks the ~70%
// dependency-stall budget.  In-flight <= 2 nt of loads (~150 VGPR) -- still
// far from R3's spill cliff.  WRITE_SIZE ~126 MB is the spill tripwire.
template<bool L1P>
DI void hconv_all(const _Float16* __restrict__ xt, _Float16* __restrict__ hb,
                  f16x8 wA0, f16x8 wA1, int w, int lane) {
  const int q = lane >> 4, m = lane & 15;
  const int K0b = (w < 2) ? 0 : 32;
  const int cb = w * 16 + q * 4;
  f32x4 zero4 = {0.f, 0.f, 0.f, 0.f};
#pragma unroll
  for (int nt = 0; nt < 4; ++nt) {
    const int row = nt * 16 + m;
    const int base = row * PAW + K0b + q * 8;
    f32x4 ax = zero4, ay = zero4, asq = zero4, axy = zero4, al1 = zero4;
#pragma unroll
    for (int ks = 0; ks < 2; ++ks) {
      const f16x8 A = ks ? wA1 : wA0;
      const int idx = (base + ks * 32) ^ ((row & 7) << 3);
      f16x8 xv = ldfrag(xt + idx);
      f16x8 yv = ldfrag(xt + TILE + idx);
      ax = mfma16(A, xv, ax);
      ay = mfma16(A, yv, ay);
      asq = mfma16(A, xv * xv + yv * yv, asq);   // v_pk_mul/fma_f16
      axy = mfma16(A, xv * yv, axy);
      if (L1P) al1 = mfma16(A, pkabs8(xv - yv), al1);
    }
    // C/D layout (m89-verified): m = (lane>>4)*4 + reg, n = lane&15.
    _Float16* wp = hb + cb * PBV + nt * 16 + m;
#pragma unroll
    for (int j = 0; j < 4; ++j) {
      wp[j * PBV] = (_Float16)ax[j];
      wp[PLANE + j * PBV] = (_Float16)ay[j];
      wp[2 * PLANE + j * PBV] = (_Float16)asq[j];
      wp[3 * PLANE + j * PBV] = (_Float16)axy[j];
      if (L1P) wp[4 * PLANE + j * PBV] = (_Float16)al1[j];
    }
    if (nt & 1) SCHED_FENCE();             // relaxed: every 2 nt
  }
}

// ---- fused vertical conv: all 4 stat planes -> 8 f32x4 accumulators ----
// A = hb data (m = col, contiguous b128), B = weight frags (n = out-row group).
// Single trailing fence: both ks's loads may pipeline (16 b128 in flight max).
DI void vconv_all(const _Float16* __restrict__ hb,
                  f16x8 w00, f16x8 w01, f16x8 w10, f16x8 w11,
                  int w, int lane, f32x4* __restrict__ acc) {
  const int q = lane >> 4, m = lane & 15;
  const int base = (w * 16 + m) * PBV + q * 8;
#pragma unroll
  for (int ks = 0; ks < 2; ++ks) {
    f16x8 B0 = ks ? w01 : w00;
    f16x8 B1 = ks ? w11 : w10;
#pragma unroll
    for (int pl = 0; pl < 4; ++pl) {
      f16x8 A = ldfrag(hb + pl * PLANE + base + ks * 32);
      acc[2 * pl]     = mfma16(A, B0, acc[2 * pl]);
      acc[2 * pl + 1] = mfma16(A, B1, acc[2 * pl + 1]);
    }
  }
  SCHED_FENCE();
}

// ---- vertical conv of |x-y| (plane 4) collapsed to scalar via uniform U ----
DI float vl1(const _Float16* __restrict__ hb, const unsigned* __restrict__ U,
             int col, int r0) {
  const _Float16* p0 = hb + 4 * PLANE + col * PBV + r0;
  float s = 0.f;
#pragma unroll
  for (int p = 0; p < 20; ++p)
    s = fdot2f(w2h(U[p]), *reinterpret_cast<const h2_t*>(p0 + 2 * p), s);
  return s;
}

// Per sigma: hconv_all | bar | vconv_all + fold (+vl1) | bar -- the R10
// 2-barrier structure (best measured, 199 us).  R14/R15: occupancy axis dead
// (3rd block never lands regardless of LDS; extra barriers cost 14-19%).
// R16: LDS instr count not the limiter.  This round: scheduling-fence
// relaxation for load-latency ILP.
template<bool LAST>
DI void do_sigma_m(int s, const _Float16* __restrict__ frh,
                   const unsigned* __restrict__ U,
                   const _Float16* __restrict__ xt, _Float16* __restrict__ hb,
                   float* __restrict__ PIcs, float& gl1s, int tid) {
  const int lane = tid & 63, w = tid >> 6;
  // weight frags [s][cls][ks][lane][8h]: shared between hconv (cls = w&1) and
  // vconv (cls = out-row group) because Delta0 = 32ks - 16cls in both.
  const f16x8* fr = reinterpret_cast<const f16x8*>(frh) + s * 256 + lane;
  f16x8 w00 = fr[0], w01 = fr[64], w10 = fr[128], w11 = fr[192];
  const bool odd = (w & 1);
  f16x8 wA0 = odd ? w10 : w00;
  f16x8 wA1 = odd ? w11 : w01;

  hconv_all<LAST>(xt, hb, wA0, wA1, w, lane);
  __syncthreads();
  f32x4 zero4 = {0.f, 0.f, 0.f, 0.f};
  f32x4 acc[8];
#pragma unroll
  for (int i = 0; i < 8; ++i) acc[i] = zero4;
  vconv_all(hb, w00, w01, w10, w11, w, lane, acc);
  if (LAST) gl1s += vl1(hb, U, tid & 63, (tid >> 6) * 8);
  // fold: acc[0..1]=mux, [2..3]=muy, [4..5]=s2, [6..7]=exy (per row-group h)
#pragma unroll
  for (int h = 0; h < 2; ++h)
#pragma unroll
    for (int j = 0; j < 4; ++j) {
      const int i = h * 4 + j;
      float a = acc[h][j], b = acc[2 + h][j];
      float m2 = a * a + b * b, mxy = a * b;
      PIcs[i] *= fmaf(2.f, acc[6 + h][j] - mxy, kC2) *
                 rcp_fast(acc[4 + h][j] - m2 + kC2);
      if (LAST)                            // luminance folded into PIcs
        PIcs[i] *= fmaf(2.f, mxy, kC1) * rcp_fast(m2 + kC1);
    }
  __syncthreads();                         // hb free for next sigma/channel
}

DI unsigned packh(float a, float b) {
  h2_t v; v.x = (_Float16)a; v.y = (_Float16)b;
  return __builtin_bit_cast(unsigned, v);
}

// ws layout (floats): [0..164] f32 1D kernels; u32 U[20] @168; weight frags
// (halfs) @208: [sigma][cls][ks][lane][8] = 10240 halfs (~20 KB).
__global__ void prep_k(const float* __restrict__ gm, float* __restrict__ ws) {
  int t = threadIdx.x;
  if (t < 165) {
    int s = t / 33, j = t % 33;
    const float* mk = gm + (3 * s) * (33 * 33);
    ws[t] = mk[16 * 33 + j] / sqrtf(mk[16 * 33 + 16]);
  }
  __syncthreads();
  if (t == 0) {
    // U[p] = sum over i=0..3, j=p-i in [0,16] of (E[j]+O[j]) halves, sigma=8
    const float* w = ws + 4 * 33;
    unsigned* U = (unsigned*)(ws + 168);
    for (int p = 0; p < 20; ++p) {
      float ux = 0.f, uy = 0.f;
      for (int i = 0; i < 4; ++i) {
        int j = p - i;
        if (j < 0 || j > 16) continue;
        ux += w[2 * j];
        if (2 * j + 1 <= 32) uy += w[2 * j + 1];
        if (j > 0) ux += w[2 * j - 1];
        uy += w[2 * j];
      }
      U[p] = packh(ux, uy);
    }
  }
  // weight fragments; k-map k = K0 + 8*(lane>>4) + i applied identically to the
  // data-operand reads, so any bijective mis-guess of the HW k-map cancels.
  _Float16* fr = (_Float16*)(ws + 208);
  const int Rs[5] = {4, 6, 12, 16, 16};
  for (int e = t; e < 10240; e += 256) {
    int s = e >> 11, r = e & 2047;
    int cls = (r >> 10) & 1, ks = (r >> 9) & 1, lane = (r >> 3) & 63, i = r & 7;
    int tp = 32 * ks - 16 * cls + 8 * (lane >> 4) + i - (lane & 15);
    int R = Rs[s], j = tp - 16 + R;
    float v = (j >= 0 && j <= 2 * R) ? ws[s * 33 + j] : 0.f;
    fr[e] = (_Float16)v;
  }
}

// 64x32 output tile, 5 hb planes: ~69.5 KB LDS, 2 blocks/CU (proven max;
// LDS-capped -> VGPR headroom to 256 is free).  (256,2): natural VGPR alloc.
// NEVER (256,3) -- twice measured (R2, R11): caps at 84 VGPR, spills 300-700MB.
__global__ __launch_bounds__(256, 2)
void msloss_k(const float* __restrict__ x, const float* __restrict__ y,
              const float* __restrict__ ws, float* __restrict__ out) {
  // xt @0 [row][col] swizzled (64x96), yt @TILE, hb @2*TILE: 5 planes [col][row]
  __shared__ __align__(16) _Float16 smem[2 * TILE + 5 * PLANE];
  __shared__ float red[4];
  _Float16* xt = smem;
  _Float16* hb = smem + 2 * TILE;
  const _Float16* frh = (const _Float16*)(ws + 208);
  const unsigned* U = (const unsigned*)(ws + 168);
  const int tid = threadIdx.x;
  const int ox = blockIdx.x * 64, oy = blockIdx.y * 32;
  const int b = blockIdx.z;

  float PIcs[8];
  float gl1s = 0.f;
#pragma unroll
  for (int i = 0; i < 8; ++i) PIcs[i] = 1.f;

  for (int c = 0; c < 3; ++c) {
    const float* xp = x + (size_t)(b * 3 + c) * (512 * 512);
    const float* yp = y + (size_t)(b * 3 + c) * (512 * 512);
    // stage 64 rows x 96 cols fp32 -> fp16, swizzled [row][col], zero halo
#pragma unroll
    for (int it = 0; it < 12; ++it) {
      int idx = it * 256 + tid;            // 64 rows x 48 colpairs
      int row = idx / 48, cp = idx % 48;
      int gy = oy + row - 16, gx = ox + cp * 2 - 16;
      bool ok = ((unsigned)gy < 512u) && ((unsigned)gx < 512u);  // gx even
      float2 xv = make_float2(0.f, 0.f), yv = make_float2(0.f, 0.f);
      if (ok) {
        xv = *reinterpret_cast<const float2*>(xp + gy * 512 + gx);
        yv = *reinterpret_cast<const float2*>(yp + gy * 512 + gx);
      }
      h2_t hx; hx.x = (_Float16)xv.x; hx.y = (_Float16)xv.y;
      h2_t hy; hy.x = (_Float16)yv.x; hy.y = (_Float16)yv.y;
      int si = (row * PAW + cp * 2) ^ ((row & 7) << 3);   // h2-safe: XOR bits>=3
      *reinterpret_cast<h2_t*>(xt + si) = hx;
      *reinterpret_cast<h2_t*>(xt + TILE + si) = hy;
    }
    __syncthreads();
    do_sigma_m<false>(0, frh, U, xt, hb, PIcs, gl1s, tid);
    do_sigma_m<false>(1, frh, U, xt, hb, PIcs, gl1s, tid);
    do_sigma_m<false>(2, frh, U, xt, hb, PIcs, gl1s, tid);
    do_sigma_m<false>(3, frh, U, xt, hb, PIcs, gl1s, tid);
    do_sigma_m<true >(4, frh, U, xt, hb, PIcs, gl1s, tid);
    // do_sigma ends with __syncthreads(): safe to restage next channel
  }

  float s = ((1.f - kALPHA) / 3.f) * gl1s;
#pragma unroll
  for (int i = 0; i < 8; ++i) s += kALPHA * (1.f - PIcs[i]);
#pragma unroll
  for (int off = 32; off > 0; off >>= 1) s += __shfl_down(s, off);
  if ((tid & 63) == 0) red[tid >> 6] = s;
  __syncthreads();
  if (tid == 0)
    atomicAdd(out, (red[0] + red[1] + red[2] + red[3]) *
                       (200.0f / (8.0f * 512.0f * 512.0f)));
}

extern "C" void kernel_launch(void* const* d_in, const int* in_sizes, int n_in,
                              void* d_out, int out_size, void* d_ws, size_t ws_size,
                              hipStream_t stream) {
  const float* x = (const float*)d_in[0];
  const float* y = (const float*)d_in[1];
  const float* gm = (const float*)d_in[2];
  float* out = (float*)d_out;
  float* ws = (float*)d_ws;   // 165 f32 + U + 20 KB weight frags

  hipMemsetAsync(d_out, 0, out_size * sizeof(float), stream);
  prep_k<<<1, 256, 0, stream>>>(gm, ws);
  msloss_k<<<dim3(8, 16, 8), 256, 0, stream>>>(x, y, ws, out);
}

// Round 18
// 264.757 us; speedup vs baseline: 1.0678x; 1.0678x over previous
//
#include <hip/hip_runtime.h>

typedef _Float16 h2_t __attribute__((ext_vector_type(2)));
typedef _Float16 f16x8 __attribute__((ext_vector_type(8)));
typedef float f32x4 __attribute__((ext_vector_type(4)));
typedef unsigned u32x4 __attribute__((ext_vector_type(4)));

#define DI __device__ __forceinline__

#if __has_builtin(__builtin_amdgcn_sched_barrier)
#define SCHED_FENCE() __builtin_amdgcn_sched_barrier(0)
#else
#define SCHED_FENCE()
#endif

constexpr int PAW = 96;          // xt pitch (halfs): 192 B rows, 16B-aligned + XOR swizzle
constexpr int PBV = 72;          // hb pitch (halfs): 144 B rows = 9*16 -> b128-aligned
constexpr int TILE = 64 * PAW;   // one staged image plane: 6144 halfs
constexpr int PLANE = 64 * PBV;  // one hb plane: 4608 halfs
constexpr float kC1 = 1.0e-4f;   // (0.01*1)^2
constexpr float kC2 = 9.0e-4f;   // (0.03*1)^2
constexpr float kALPHA = 0.025f;

DI float rcp_fast(float v) { return __builtin_amdgcn_rcpf(v); }

DI float fdot2f(h2_t a, h2_t b, float c) {
#if __has_builtin(__builtin_amdgcn_fdot2)
  return __builtin_amdgcn_fdot2(a, b, c, false);   // v_dot2_f32_f16
#else
  return c + (float)(a.x) * (float)(b.x) + (float)(a.y) * (float)(b.y);
#endif
}

DI h2_t w2h(unsigned u) { return __builtin_bit_cast(h2_t, u); }

DI f16x8 ldfrag(const _Float16* __restrict__ p) {
  return *reinterpret_cast<const f16x8*>(p);
}

DI f32x4 mfma16(f16x8 a, f16x8 b, f32x4 c) {
  return __builtin_amdgcn_mfma_f32_16x16x32_f16(a, b, c, 0, 0, 0);
}

DI f16x8 pkabs8(f16x8 v) {
  u32x4 u = __builtin_bit_cast(u32x4, v);
  u32x4 msk = {0x7FFF7FFFu, 0x7FFF7FFFu, 0x7FFF7FFFu, 0x7FFF7FFFu};
  u &= msk;
  return __builtin_bit_cast(f16x8, u);
}

// ---- fused horizontal conv as MFMA: all fields in ONE pass (R10 layout) ----
// A = weights (m = out-col), B = data frags.  Fields {x,y,x^2+y^2,x*y(,|x-y|)}
// -> planes 0..3(,4) from ONE set of xt/yt reads.  b16 stores (R16 lesson:
// b64 operand-swap DOUBLED bank conflicts -- instr count is NOT the limiter).
// Fences every 2 nt (R17).
template<bool L1P>
DI void hconv_all(const _Float16* __restrict__ xt, _Float16* __restrict__ hb,
                  f16x8 wA0, f16x8 wA1, int w, int lane) {
  const int q = lane >> 4, m = lane & 15;
  const int K0b = (w < 2) ? 0 : 32;
  const int cb = w * 16 + q * 4;
  f32x4 zero4 = {0.f, 0.f, 0.f, 0.f};
#pragma unroll
  for (int nt = 0; nt < 4; ++nt) {
    const int row = nt * 16 + m;
    const int base = row * PAW + K0b + q * 8;
    f32x4 ax = zero4, ay = zero4, asq = zero4, axy = zero4, al1 = zero4;
#pragma unroll
    for (int ks = 0; ks < 2; ++ks) {
      const f16x8 A = ks ? wA1 : wA0;
      const int idx = (base + ks * 32) ^ ((row & 7) << 3);
      f16x8 xv = ldfrag(xt + idx);
      f16x8 yv = ldfrag(xt + TILE + idx);
      ax = mfma16(A, xv, ax);
      ay = mfma16(A, yv, ay);
      asq = mfma16(A, xv * xv + yv * yv, asq);   // v_pk_mul/fma_f16
      axy = mfma16(A, xv * yv, axy);
      if (L1P) al1 = mfma16(A, pkabs8(xv - yv), al1);
    }
    // C/D layout (m89-verified): m = (lane>>4)*4 + reg, n = lane&15.
    _Float16* wp = hb + cb * PBV + nt * 16 + m;
#pragma unroll
    for (int j = 0; j < 4; ++j) {
      wp[j * PBV] = (_Float16)ax[j];
      wp[PLANE + j * PBV] = (_Float16)ay[j];
      wp[2 * PLANE + j * PBV] = (_Float16)asq[j];
      wp[3 * PLANE + j * PBV] = (_Float16)axy[j];
      if (L1P) wp[4 * PLANE + j * PBV] = (_Float16)al1[j];
    }
    if (nt & 1) SCHED_FENCE();             // relaxed: every 2 nt
  }
}

// ---- fused vertical conv: all 4 stat planes -> 8 f32x4 accumulators ----
// A = hb data (m = col, contiguous b128), B = weight frags (n = out-row group).
DI void vconv_all(const _Float16* __restrict__ hb,
                  f16x8 w00, f16x8 w01, f16x8 w10, f16x8 w11,
                  int w, int lane, f32x4* __restrict__ acc) {
  const int q = lane >> 4, m = lane & 15;
  const int base = (w * 16 + m) * PBV + q * 8;
#pragma unroll
  for (int ks = 0; ks < 2; ++ks) {
    f16x8 B0 = ks ? w01 : w00;
    f16x8 B1 = ks ? w11 : w10;
#pragma unroll
    for (int pl = 0; pl < 4; ++pl) {
      f16x8 A = ldfrag(hb + pl * PLANE + base + ks * 32);
      acc[2 * pl]     = mfma16(A, B0, acc[2 * pl]);
      acc[2 * pl + 1] = mfma16(A, B1, acc[2 * pl + 1]);
    }
  }
  SCHED_FENCE();
}

// ---- vertical conv of |x-y| (plane 4) collapsed to scalar via uniform U ----
DI float vl1(const _Float16* __restrict__ hb, const unsigned* __restrict__ U,
             int col, int r0) {
  const _Float16* p0 = hb + 4 * PLANE + col * PBV + r0;
  float s = 0.f;
#pragma unroll
  for (int p = 0; p < 20; ++p)
    s = fdot2f(w2h(U[p]), *reinterpret_cast<const h2_t*>(p0 + 2 * p), s);
  return s;
}

// Per sigma: hconv_all | bar | vconv_all + fold (+vl1) | bar (R10 structure).
template<bool LAST>
DI void do_sigma_m(int s, const _Float16* __restrict__ frh,
                   const unsigned* __restrict__ U,
                   const _Float16* __restrict__ xt, _Float16* __restrict__ hb,
                   float* __restrict__ PIcs, float& gl1s, int tid) {
  const int lane = tid & 63, w = tid >> 6;
  // weight frags [s][cls][ks][lane][8h]: shared between hconv (cls = w&1) and
  // vconv (cls = out-row group) because Delta0 = 32ks - 16cls in both.
  const f16x8* fr = reinterpret_cast<const f16x8*>(frh) + s * 256 + lane;
  f16x8 w00 = fr[0], w01 = fr[64], w10 = fr[128], w11 = fr[192];
  const bool odd = (w & 1);
  f16x8 wA0 = odd ? w10 : w00;
  f16x8 wA1 = odd ? w11 : w01;

  hconv_all<LAST>(xt, hb, wA0, wA1, w, lane);
  __syncthreads();
  f32x4 zero4 = {0.f, 0.f, 0.f, 0.f};
  f32x4 acc[8];
#pragma unroll
  for (int i = 0; i < 8; ++i) acc[i] = zero4;
  vconv_all(hb, w00, w01, w10, w11, w, lane, acc);
  if (LAST) gl1s += vl1(hb, U, tid & 63, (tid >> 6) * 8);
  // fold: acc[0..1]=mux, [2..3]=muy, [4..5]=s2, [6..7]=exy (per row-group h)
#pragma unroll
  for (int h = 0; h < 2; ++h)
#pragma unroll
    for (int j = 0; j < 4; ++j) {
      const int i = h * 4 + j;
      float a = acc[h][j], b = acc[2 + h][j];
      float m2 = a * a + b * b, mxy = a * b;
      PIcs[i] *= fmaf(2.f, acc[6 + h][j] - mxy, kC2) *
                 rcp_fast(acc[4 + h][j] - m2 + kC2);
      if (LAST)                            // luminance folded into PIcs
        PIcs[i] *= fmaf(2.f, mxy, kC1) * rcp_fast(m2 + kC1);
    }
  __syncthreads();                         // hb free for next sigma/channel
}

DI unsigned packh(float a, float b) {
  h2_t v; v.x = (_Float16)a; v.y = (_Float16)b;
  return __builtin_bit_cast(unsigned, v);
}

// ws layout (floats): [0..164] f32 1D kernels; u32 U[20] @168; weight frags
// (halfs) @208: [sigma][cls][ks][lane][8] = 10240 halfs (~20 KB).
__global__ void prep_k(const float* __restrict__ gm, float* __restrict__ ws) {
  int t = threadIdx.x;
  if (t < 165) {
    int s = t / 33, j = t % 33;
    const float* mk = gm + (3 * s) * (33 * 33);
    ws[t] = mk[16 * 33 + j] / sqrtf(mk[16 * 33 + 16]);
  }
  __syncthreads();
  if (t == 0) {
    // U[p] = sum over i=0..3, j=p-i in [0,16] of (E[j]+O[j]) halves, sigma=8
    const float* w = ws + 4 * 33;
    unsigned* U = (unsigned*)(ws + 168);
    for (int p = 0; p < 20; ++p) {
      float ux = 0.f, uy = 0.f;
      for (int i = 0; i < 4; ++i) {
        int j = p - i;
        if (j < 0 || j > 16) continue;
        ux += w[2 * j];
        if (2 * j + 1 <= 32) uy += w[2 * j + 1];
        if (j > 0) ux += w[2 * j - 1];
        uy += w[2 * j];
      }
      U[p] = packh(ux, uy);
    }
  }
  // weight fragments; k-map k = K0 + 8*(lane>>4) + i applied identically to the
  // data-operand reads, so any bijective mis-guess of the HW k-map cancels.
  _Float16* fr = (_Float16*)(ws + 208);
  const int Rs[5] = {4, 6, 12, 16, 16};
  for (int e = t; e < 10240; e += 256) {
    int s = e >> 11, r = e & 2047;
    int cls = (r >> 10) & 1, ks = (r >> 9) & 1, lane = (r >> 3) & 63, i = r & 7;
    int tp = 32 * ks - 16 * cls + 8 * (lane >> 4) + i - (lane & 15);
    int R = Rs[s], j = tp - 16 + R;
    float v = (j >= 0 && j <= 2 * R) ? ws[s * 33 + j] : 0.f;
    fr[e] = (_Float16)v;
  }
}

// CLIFF PROBE (R17 lesson): reported VGPR_Count has been budget/2 in EVERY
// round (128 @ (256,2) budget 256; 84 @ (256,3) budget ~170) regardless of
// code -- hypothesis: the allocator always consumes its full budget and the
// persistent 117-142 MB WRITE_SIZE + inflated FETCH is spill traffic at the
// cliff (scratch streams also evict the 50 MB image set from L2/L3; R0's
// non-MFMA kernel had FETCH 52 / WRITE 13 MB).  (256,1) doubles the budget
// to 512.  Decisive readout: WRITE < 25 MB => cliff confirmed (then tune
// pressure to fit spill-free at 2 blocks); WRITE ~140 MB => theory dead.
// Occupancy may halve (1 block/CU) -- accepted diagnostic cost.
__global__ __launch_bounds__(256, 1)
void msloss_k(const float* __restrict__ x, const float* __restrict__ y,
              const float* __restrict__ ws, float* __restrict__ out) {
  // xt @0 [row][col] swizzled (64x96), yt @TILE, hb @2*TILE: 5 planes [col][row]
  __shared__ __align__(16) _Float16 smem[2 * TILE + 5 * PLANE];
  __shared__ float red[4];
  _Float16* xt = smem;
  _Float16* hb = smem + 2 * TILE;
  const _Float16* frh = (const _Float16*)(ws + 208);
  const unsigned* U = (const unsigned*)(ws + 168);
  const int tid = threadIdx.x;
  const int ox = blockIdx.x * 64, oy = blockIdx.y * 32;
  const int b = blockIdx.z;

  float PIcs[8];
  float gl1s = 0.f;
#pragma unroll
  for (int i = 0; i < 8; ++i) PIcs[i] = 1.f;

  for (int c = 0; c < 3; ++c) {
    const float* xp = x + (size_t)(b * 3 + c) * (512 * 512);
    const float* yp = y + (size_t)(b * 3 + c) * (512 * 512);
    // stage 64 rows x 96 cols fp32 -> fp16, swizzled [row][col], zero halo
#pragma unroll
    for (int it = 0; it < 12; ++it) {
      int idx = it * 256 + tid;            // 64 rows x 48 colpairs
      int row = idx / 48, cp = idx % 48;
      int gy = oy + row - 16, gx = ox + cp * 2 - 16;
      bool ok = ((unsigned)gy < 512u) && ((unsigned)gx < 512u);  // gx even
      float2 xv = make_float2(0.f, 0.f), yv = make_float2(0.f, 0.f);
      if (ok) {
        xv = *reinterpret_cast<const float2*>(xp + gy * 512 + gx);
        yv = *reinterpret_cast<const float2*>(yp + gy * 512 + gx);
      }
      h2_t hx; hx.x = (_Float16)xv.x; hx.y = (_Float16)xv.y;
      h2_t hy; hy.x = (_Float16)yv.x; hy.y = (_Float16)yv.y;
      int si = (row * PAW + cp * 2) ^ ((row & 7) << 3);   // h2-safe: XOR bits>=3
      *reinterpret_cast<h2_t*>(xt + si) = hx;
      *reinterpret_cast<h2_t*>(xt + TILE + si) = hy;
    }
    __syncthreads();
    do_sigma_m<false>(0, frh, U, xt, hb, PIcs, gl1s, tid);
    do_sigma_m<false>(1, frh, U, xt, hb, PIcs, gl1s, tid);
    do_sigma_m<false>(2, frh, U, xt, hb, PIcs, gl1s, tid);
    do_sigma_m<false>(3, frh, U, xt, hb, PIcs, gl1s, tid);
    do_sigma_m<true >(4, frh, U, xt, hb, PIcs, gl1s, tid);
    // do_sigma ends with __syncthreads(): safe to restage next channel
  }

  float s = ((1.f - kALPHA) / 3.f) * gl1s;
#pragma unroll
  for (int i = 0; i < 8; ++i) s += kALPHA * (1.f - PIcs[i]);
#pragma unroll
  for (int off = 32; off > 0; off >>= 1) s += __shfl_down(s, off);
  if ((tid & 63) == 0) red[tid >> 6] = s;
  __syncthreads();
  if (tid == 0)
    atomicAdd(out, (red[0] + red[1] + red[2] + red[3]) *
                       (200.0f / (8.0f * 512.0f * 512.0f)));
}

extern "C" void kernel_launch(void* const* d_in, const int* in_sizes, int n_in,
                              void* d_out, int out_size, void* d_ws, size_t ws_size,
                              hipStream_t stream) {
  const float* x = (const float*)d_in[0];
  const float* y = (const float*)d_in[1];
  const float* gm = (const float*)d_in[2];
  float* out = (float*)d_out;
  float* ws = (float*)d_ws;   // 165 f32 + U + 20 KB weight frags

  hipMemsetAsync(d_out, 0, out_size * sizeof(float), stream);
  prep_k<<<1, 256, 0, stream>>>(gm, ws);
  msloss_k<<<dim3(8, 16, 8), 256, 0, stream>>>(x, y, ws, out);
}

// Round 19
// 248.785 us; speedup vs baseline: 1.1363x; 1.0642x over previous
//
#include <hip/hip_runtime.h>

typedef _Float16 h2_t __attribute__((ext_vector_type(2)));
typedef _Float16 f16x8 __attribute__((ext_vector_type(8)));
typedef float f32x4 __attribute__((ext_vector_type(4)));
typedef unsigned u32x4 __attribute__((ext_vector_type(4)));

#define DI __device__ __forceinline__

constexpr int PAW = 96;          // xt pitch (halfs): 192 B rows, 16B-aligned + XOR swizzle
constexpr int PBV = 72;          // hb pitch (halfs): 144 B rows = 9*16 -> b128-aligned
constexpr int TILE = 64 * PAW;   // one staged image plane: 6144 halfs
constexpr int PLANE = 64 * PBV;  // one hb plane: 4608 halfs
constexpr float kC1 = 1.0e-4f;   // (0.01*1)^2
constexpr float kC2 = 9.0e-4f;   // (0.03*1)^2
constexpr float kALPHA = 0.025f;

DI float rcp_fast(float v) { return __builtin_amdgcn_rcpf(v); }

DI float fdot2f(h2_t a, h2_t b, float c) {
#if __has_builtin(__builtin_amdgcn_fdot2)
  return __builtin_amdgcn_fdot2(a, b, c, false);   // v_dot2_f32_f16
#else
  return c + (float)(a.x) * (float)(b.x) + (float)(a.y) * (float)(b.y);
#endif
}

DI h2_t w2h(unsigned u) { return __builtin_bit_cast(h2_t, u); }

DI f16x8 ldfrag(const _Float16* __restrict__ p) {
  return *reinterpret_cast<const f16x8*>(p);
}

DI f32x4 mfma16(f16x8 a, f16x8 b, f32x4 c) {
  return __builtin_amdgcn_mfma_f32_16x16x32_f16(a, b, c, 0, 0, 0);
}

DI f16x8 pkabs8(f16x8 v) {
  u32x4 u = __builtin_bit_cast(u32x4, v);
  u32x4 msk = {0x7FFF7FFFu, 0x7FFF7FFFu, 0x7FFF7FFFu, 0x7FFF7FFFu};
  u &= msk;
  return __builtin_bit_cast(f16x8, u);
}

// ---- fused horizontal conv as MFMA: all fields in ONE pass (R10 layout) ----
// A = weights (m = out-col), B = data frags.  Fields {x,y,x^2+y^2,x*y(,|x-y|)}
// -> planes 0..3(,4) from ONE set of xt/yt reads.  b16 stores (R16: b64
// operand-swap doubled bank conflicts).  NO SCHED FENCES (R18 regime): at
// (256,1) / 1 wave/SIMD / zero spill, ILP is the ONLY latency-hiding
// mechanism and VGPR headroom 220->256 is real.  R17's fence test was run
// at cap-128 (contaminated by spill); this is the clean re-run.
// WRITE_SIZE is the tripwire: >50 MB => scheduler blew the 256 cap.
template<bool L1P>
DI void hconv_all(const _Float16* __restrict__ xt, _Float16* __restrict__ hb,
                  f16x8 wA0, f16x8 wA1, int w, int lane) {
  const int q = lane >> 4, m = lane & 15;
  const int K0b = (w < 2) ? 0 : 32;
  const int cb = w * 16 + q * 4;
  f32x4 zero4 = {0.f, 0.f, 0.f, 0.f};
#pragma unroll
  for (int nt = 0; nt < 4; ++nt) {
    const int row = nt * 16 + m;
    const int base = row * PAW + K0b + q * 8;
    f32x4 ax = zero4, ay = zero4, asq = zero4, axy = zero4, al1 = zero4;
#pragma unroll
    for (int ks = 0; ks < 2; ++ks) {
      const f16x8 A = ks ? wA1 : wA0;
      const int idx = (base + ks * 32) ^ ((row & 7) << 3);
      f16x8 xv = ldfrag(xt + idx);
      f16x8 yv = ldfrag(xt + TILE + idx);
      ax = mfma16(A, xv, ax);
      ay = mfma16(A, yv, ay);
      asq = mfma16(A, xv * xv + yv * yv, asq);   // v_pk_mul/fma_f16
      axy = mfma16(A, xv * yv, axy);
      if (L1P) al1 = mfma16(A, pkabs8(xv - yv), al1);
    }
    // C/D layout (m89-verified): m = (lane>>4)*4 + reg, n = lane&15.
    _Float16* wp = hb + cb * PBV + nt * 16 + m;
#pragma unroll
    for (int j = 0; j < 4; ++j) {
      wp[j * PBV] = (_Float16)ax[j];
      wp[PLANE + j * PBV] = (_Float16)ay[j];
      wp[2 * PLANE + j * PBV] = (_Float16)asq[j];
      wp[3 * PLANE + j * PBV] = (_Float16)axy[j];
      if (L1P) wp[4 * PLANE + j * PBV] = (_Float16)al1[j];
    }
  }
}

// ---- fused vertical conv: all 4 stat planes -> 8 f32x4 accumulators ----
// A = hb data (m = col, contiguous b128), B = weight frags (n = out-row group).
DI void vconv_all(const _Float16* __restrict__ hb,
                  f16x8 w00, f16x8 w01, f16x8 w10, f16x8 w11,
                  int w, int lane, f32x4* __restrict__ acc) {
  const int q = lane >> 4, m = lane & 15;
  const int base = (w * 16 + m) * PBV + q * 8;
#pragma unroll
  for (int ks = 0; ks < 2; ++ks) {
    f16x8 B0 = ks ? w01 : w00;
    f16x8 B1 = ks ? w11 : w10;
#pragma unroll
    for (int pl = 0; pl < 4; ++pl) {
      f16x8 A = ldfrag(hb + pl * PLANE + base + ks * 32);
      acc[2 * pl]     = mfma16(A, B0, acc[2 * pl]);
      acc[2 * pl + 1] = mfma16(A, B1, acc[2 * pl + 1]);
    }
  }
}

// ---- vertical conv of |x-y| (plane 4) collapsed to scalar via uniform U ----
DI float vl1(const _Float16* __restrict__ hb, const unsigned* __restrict__ U,
             int col, int r0) {
  const _Float16* p0 = hb + 4 * PLANE + col * PBV + r0;
  float s = 0.f;
#pragma unroll
  for (int p = 0; p < 20; ++p)
    s = fdot2f(w2h(U[p]), *reinterpret_cast<const h2_t*>(p0 + 2 * p), s);
  return s;
}

// Per sigma: hconv_all | bar | vconv_all + fold (+vl1) | bar (R10 structure).
template<bool LAST>
DI void do_sigma_m(int s, const _Float16* __restrict__ frh,
                   const unsigned* __restrict__ U,
                   const _Float16* __restrict__ xt, _Float16* __restrict__ hb,
                   float* __restrict__ PIcs, float& gl1s, int tid) {
  const int lane = tid & 63, w = tid >> 6;
  // weight frags [s][cls][ks][lane][8h]: shared between hconv (cls = w&1) and
  // vconv (cls = out-row group) because Delta0 = 32ks - 16cls in both.
  const f16x8* fr = reinterpret_cast<const f16x8*>(frh) + s * 256 + lane;
  f16x8 w00 = fr[0], w01 = fr[64], w10 = fr[128], w11 = fr[192];
  const bool odd = (w & 1);
  f16x8 wA0 = odd ? w10 : w00;
  f16x8 wA1 = odd ? w11 : w01;

  hconv_all<LAST>(xt, hb, wA0, wA1, w, lane);
  __syncthreads();
  f32x4 zero4 = {0.f, 0.f, 0.f, 0.f};
  f32x4 acc[8];
#pragma unroll
  for (int i = 0; i < 8; ++i) acc[i] = zero4;
  vconv_all(hb, w00, w01, w10, w11, w, lane, acc);
  if (LAST) gl1s += vl1(hb, U, tid & 63, (tid >> 6) * 8);
  // fold: acc[0..1]=mux, [2..3]=muy, [4..5]=s2, [6..7]=exy (per row-group h)
#pragma unroll
  for (int h = 0; h < 2; ++h)
#pragma unroll
    for (int j = 0; j < 4; ++j) {
      const int i = h * 4 + j;
      float a = acc[h][j], b = acc[2 + h][j];
      float m2 = a * a + b * b, mxy = a * b;
      PIcs[i] *= fmaf(2.f, acc[6 + h][j] - mxy, kC2) *
                 rcp_fast(acc[4 + h][j] - m2 + kC2);
      if (LAST)                            // luminance folded into PIcs
        PIcs[i] *= fmaf(2.f, mxy, kC1) * rcp_fast(m2 + kC1);
    }
  __syncthreads();                         // hb free for next sigma/channel
}

DI unsigned packh(float a, float b) {
  h2_t v; v.x = (_Float16)a; v.y = (_Float16)b;
  return __builtin_bit_cast(unsigned, v);
}

// ws layout (floats): [0..164] f32 1D kernels; u32 U[20] @168; weight frags
// (halfs) @208: [sigma][cls][ks][lane][8] = 10240 halfs (~20 KB).
__global__ void prep_k(const float* __restrict__ gm, float* __restrict__ ws) {
  int t = threadIdx.x;
  if (t < 165) {
    int s = t / 33, j = t % 33;
    const float* mk = gm + (3 * s) * (33 * 33);
    ws[t] = mk[16 * 33 + j] / sqrtf(mk[16 * 33 + 16]);
  }
  __syncthreads();
  if (t == 0) {
    // U[p] = sum over i=0..3, j=p-i in [0,16] of (E[j]+O[j]) halves, sigma=8
    const float* w = ws + 4 * 33;
    unsigned* U = (unsigned*)(ws + 168);
    for (int p = 0; p < 20; ++p) {
      float ux = 0.f, uy = 0.f;
      for (int i = 0; i < 4; ++i) {
        int j = p - i;
        if (j < 0 || j > 16) continue;
        ux += w[2 * j];
        if (2 * j + 1 <= 32) uy += w[2 * j + 1];
        if (j > 0) ux += w[2 * j - 1];
        uy += w[2 * j];
      }
      U[p] = packh(ux, uy);
    }
  }
  // weight fragments; k-map k = K0 + 8*(lane>>4) + i applied identically to the
  // data-operand reads, so any bijective mis-guess of the HW k-map cancels.
  _Float16* fr = (_Float16*)(ws + 208);
  const int Rs[5] = {4, 6, 12, 16, 16};
  for (int e = t; e < 10240; e += 256) {
    int s = e >> 11, r = e & 2047;
    int cls = (r >> 10) & 1, ks = (r >> 9) & 1, lane = (r >> 3) & 63, i = r & 7;
    int tp = 32 * ks - 16 * cls + 8 * (lane >> 4) + i - (lane & 15);
    int R = Rs[s], j = tp - 16 + R;
    float v = (j >= 0 && j <= 2 * R) ? ws[s * 33 + j] : 0.f;
    fr[e] = (_Float16)v;
  }
}

// REGIME (established R18): (256,1) -> compiler VGPR cap 256 (reported),
// true pressure ~220 -> ZERO spill (WRITE 32 KB, FETCH 46 MB = compulsory).
// VGPR model: waves/SIMD = floor(512 / (2 x reported)) -> 220 => 1 wave/SIMD,
// 1 block/CU (occupancy ~11%).  Spill-free 2-waves/SIMD would need <=128
// reported (~92-reg cut) -- not incremental.  At 1 wave/SIMD, ILP is the
// only latency hiding -> fences removed this round.
// NEVER (256,2)/(256,3): caps 128/84 -> 117-400 MB scratch spill (R3-R17).
__global__ __launch_bounds__(256, 1)
void msloss_k(const float* __restrict__ x, const float* __restrict__ y,
              const float* __restrict__ ws, float* __restrict__ out) {
  // xt @0 [row][col] swizzled (64x96), yt @TILE, hb @2*TILE: 5 planes [col][row]
  __shared__ __align__(16) _Float16 smem[2 * TILE + 5 * PLANE];
  __shared__ float red[4];
  _Float16* xt = smem;
  _Float16* hb = smem + 2 * TILE;
  const _Float16* frh = (const _Float16*)(ws + 208);
  const unsigned* U = (const unsigned*)(ws + 168);
  const int tid = threadIdx.x;
  const int ox = blockIdx.x * 64, oy = blockIdx.y * 32;
  const int b = blockIdx.z;

  float PIcs[8];
  float gl1s = 0.f;
#pragma unroll
  for (int i = 0; i < 8; ++i) PIcs[i] = 1.f;

  for (int c = 0; c < 3; ++c) {
    const float* xp = x + (size_t)(b * 3 + c) * (512 * 512);
    const float* yp = y + (size_t)(b * 3 + c) * (512 * 512);
    // stage 64 rows x 96 cols fp32 -> fp16, swizzled [row][col], zero halo
#pragma unroll
    for (int it = 0; it < 12; ++it) {
      int idx = it * 256 + tid;            // 64 rows x 48 colpairs
      int row = idx / 48, cp = idx % 48;
      int gy = oy + row - 16, gx = ox + cp * 2 - 16;
      bool ok = ((unsigned)gy < 512u) && ((unsigned)gx < 512u);  // gx even
      float2 xv = make_float2(0.f, 0.f), yv = make_float2(0.f, 0.f);
      if (ok) {
        xv = *reinterpret_cast<const float2*>(xp + gy * 512 + gx);
        yv = *reinterpret_cast<const float2*>(yp + gy * 512 + gx);
      }
      h2_t hx; hx.x = (_Float16)xv.x; hx.y = (_Float16)xv.y;
      h2_t hy; hy.x = (_Float16)yv.x; hy.y = (_Float16)yv.y;
      int si = (row * PAW + cp * 2) ^ ((row & 7) << 3);   // h2-safe: XOR bits>=3
      *reinterpret_cast<h2_t*>(xt + si) = hx;
      *reinterpret_cast<h2_t*>(xt + TILE + si) = hy;
    }
    __syncthreads();
    do_sigma_m<false>(0, frh, U, xt, hb, PIcs, gl1s, tid);
    do_sigma_m<false>(1, frh, U, xt, hb, PIcs, gl1s, tid);
    do_sigma_m<false>(2, frh, U, xt, hb, PIcs, gl1s, tid);
    do_sigma_m<false>(3, frh, U, xt, hb, PIcs, gl1s, tid);
    do_sigma_m<true >(4, frh, U, xt, hb, PIcs, gl1s, tid);
    // do_sigma ends with __syncthreads(): safe to restage next channel
  }

  float s = ((1.f - kALPHA) / 3.f) * gl1s;
#pragma unroll
  for (int i = 0; i < 8; ++i) s += kALPHA * (1.f - PIcs[i]);
#pragma unroll
  for (int off = 32; off > 0; off >>= 1) s += __shfl_down(s, off);
  if ((tid & 63) == 0) red[tid >> 6] = s;
  __syncthreads();
  if (tid == 0)
    atomicAdd(out, (red[0] + red[1] + red[2] + red[3]) *
                       (200.0f / (8.0f * 512.0f * 512.0f)));
}

extern "C" void kernel_launch(void* const* d_in, const int* in_sizes, int n_in,
                              void* d_out, int out_size, void* d_ws, size_t ws_size,
                              hipStream_t stream) {
  const float* x = (const float*)d_in[0];
  const float* y = (const float*)d_in[1];
  const float* gm = (const float*)d_in[2];
  float* out = (float*)d_out;
  float* ws = (float*)d_ws;   // 165 f32 + U + 20 KB weight frags

  hipMemsetAsync(d_out, 0, out_size * sizeof(float), stream);
  prep_k<<<1, 256, 0, stream>>>(gm, ws);
  msloss_k<<<dim3(8, 16, 8), 256, 0, stream>>>(x, y, ws, out);
}